// Round 1
// baseline (1029.295 us; speedup 1.0000x reference)
//
#include <hip/hip_runtime.h>
#include <hip/hip_bf16.h>

#define BB 4
#define NN 10000
#define EE 320000
#define HH 8
#define DD 256

typedef float f4 __attribute__((ext_vector_type(4)));
typedef short s8v __attribute__((ext_vector_type(8)));
typedef unsigned short u16x8 __attribute__((ext_vector_type(8)));

__device__ __forceinline__ unsigned short f2bf(float f) {
  unsigned int u = __float_as_uint(f);
  u += 0x7FFFu + ((u >> 16) & 1u);
  return (unsigned short)(u >> 16);
}
__device__ __forceinline__ unsigned int ordf(float f) {
  unsigned int u = __float_as_uint(f);
  return (u & 0x80000000u) ? ~u : (u | 0x80000000u);
}
__device__ __forceinline__ float unordf(unsigned int u) {
  unsigned int b = (u & 0x80000000u) ? (u & 0x7FFFFFFFu) : ~u;
  return __uint_as_float(b);
}

// ---------------- W transpose + bf16 convert: Wt[n][k] = bf16(W[k][n]) ----------------
__global__ __launch_bounds__(256) void k_transpose(const float* __restrict__ W,
                                                   unsigned short* __restrict__ Wt) {
  __shared__ float tile[64][65];
  const int n0 = blockIdx.x * 64, k0 = blockIdx.y * 64;
  for (int i = threadIdx.x; i < 4096; i += 256) {
    int kk = i >> 6, nn = i & 63;
    tile[kk][nn] = W[(size_t)(k0 + kk) * 256 + n0 + nn];
  }
  __syncthreads();
  for (int i = threadIdx.x; i < 4096; i += 256) {
    int nn = i >> 6, kk = i & 63;
    Wt[(size_t)(n0 + nn) * 256 + (k0 + kk)] = f2bf(tile[kk][nn]);
  }
}

// ---------------- GEMM: wx[row][col] = sum_k x[row][k] * W[k][col], bf16 MFMA ----------------
__global__ __launch_bounds__(256, 2) void k_gemm(const float* __restrict__ x,
                                                 const unsigned short* __restrict__ Wt,
                                                 float* __restrict__ wx) {
  __shared__ unsigned short sA[64][40];   // [row][k], padded
  __shared__ unsigned short sB[256][40];  // [col][k] (= W^T), padded
  const int tid = threadIdx.x;
  const int lane = tid & 63;
  const int wv = tid >> 6;
  const int row0 = blockIdx.x << 6;
  const int fr = lane & 15;
  const int fg = lane >> 4;
  f4 acc[4][4] = {};
  const int ar = tid >> 2;          // 0..63 staging row
  const int ak = (tid & 3) << 3;    // 0,8,16,24 staging k

  for (int k0 = 0; k0 < 256; k0 += 32) {
    // stage A tile (f32 -> bf16)
    const float* xp = x + (size_t)(row0 + ar) * 256 + k0 + ak;
    f4 v0 = *(const f4*)xp;
    f4 v1 = *(const f4*)(xp + 4);
    u16x8 av;
    av[0] = f2bf(v0[0]); av[1] = f2bf(v0[1]); av[2] = f2bf(v0[2]); av[3] = f2bf(v0[3]);
    av[4] = f2bf(v1[0]); av[5] = f2bf(v1[1]); av[6] = f2bf(v1[2]); av[7] = f2bf(v1[3]);
    *(u16x8*)&sA[ar][ak] = av;
    // stage B tile (already bf16 W^T in ws)
#pragma unroll
    for (int j = 0; j < 4; ++j) {
      int ci = tid + (j << 8);
      int col = ci >> 2;
      int ks = (ci & 3) << 3;
      *(u16x8*)&sB[col][ks] = *(const u16x8*)(Wt + (size_t)col * 256 + k0 + ks);
    }
    __syncthreads();
    s8v afr[4], bfr[4];
#pragma unroll
    for (int m = 0; m < 4; ++m) afr[m] = *(const s8v*)&sA[m * 16 + fr][fg << 3];
#pragma unroll
    for (int n = 0; n < 4; ++n) bfr[n] = *(const s8v*)&sB[wv * 64 + n * 16 + fr][fg << 3];
#pragma unroll
    for (int m = 0; m < 4; ++m)
#pragma unroll
      for (int n = 0; n < 4; ++n)
        acc[m][n] = __builtin_amdgcn_mfma_f32_16x16x32_bf16(afr[m], bfr[n], acc[m][n], 0, 0, 0);
    __syncthreads();
  }
  // epilogue: D[row][col], col = lane&15, row = (lane>>4)*4 + q  (m89-verified)
#pragma unroll
  for (int m = 0; m < 4; ++m)
#pragma unroll
    for (int n = 0; n < 4; ++n) {
      int col = wv * 64 + n * 16 + fr;
#pragma unroll
      for (int q = 0; q < 4; ++q) {
        int row = row0 + m * 16 + fg * 4 + q;
        wx[(size_t)row * 256 + col] = acc[m][n][q];
      }
    }
}

// ---------------- per-node head scores: s_src[row][h] = sum_dk wx[row][h*32+dk]*a[dk] ----------------
__global__ __launch_bounds__(256) void k_score(const float* __restrict__ wx,
                                               const float* __restrict__ a,
                                               float* __restrict__ s_src,
                                               float* __restrict__ s_dst) {
  const int row = blockIdx.x * 4 + (threadIdx.x >> 6);
  const int lane = threadIdx.x & 63;
  f4 v = *(const f4*)(wx + (size_t)row * 256 + lane * 4);
  const int head = lane >> 3;
  const int dk = (lane & 7) << 2;
  float ps = 0.f, pd = 0.f;
#pragma unroll
  for (int j = 0; j < 4; ++j) {
    ps += v[j] * a[dk + j];
    pd += v[j] * a[32 + dk + j];
  }
  ps += __shfl_xor(ps, 1); ps += __shfl_xor(ps, 2); ps += __shfl_xor(ps, 4);
  pd += __shfl_xor(pd, 1); pd += __shfl_xor(pd, 2); pd += __shfl_xor(pd, 4);
  if ((lane & 7) == 0) {
    s_src[(size_t)row * 8 + head] = ps;
    s_dst[(size_t)row * 8 + head] = pd;
  }
}

// ---------------- edge pass common: e_lin + leaky relu ----------------
__device__ __forceinline__ int edge_el(const int* __restrict__ edge,
                                       const float* __restrict__ s_src,
                                       const float* __restrict__ s_dst,
                                       int idx, float el[8]) {
  const int b = idx / EE;
  const int e = idx - b * EE;
  const int src = edge[(size_t)b * 2 * EE + e];
  const int dst = edge[(size_t)b * 2 * EE + EE + e];
  const int seg = b * NN + src;
  const f4* ss = (const f4*)(s_src + (size_t)seg * 8);
  const f4* sd = (const f4*)(s_dst + ((size_t)b * NN + dst) * 8);
  f4 a0 = ss[0] + sd[0];
  f4 a1 = ss[1] + sd[1];
#pragma unroll
  for (int j = 0; j < 4; ++j) {
    float t0 = a0[j]; el[j]     = t0 >= 0.f ? t0 : 0.2f * t0;
    float t1 = a1[j]; el[4 + j] = t1 >= 0.f ? t1 : 0.2f * t1;
  }
  return seg;
}

__global__ __launch_bounds__(256) void k_max(const int* __restrict__ edge,
                                             const float* __restrict__ s_src,
                                             const float* __restrict__ s_dst,
                                             unsigned int* __restrict__ mx) {
  const int idx = blockIdx.x * 256 + threadIdx.x;
  float el[8];
  const int seg = edge_el(edge, s_src, s_dst, idx, el);
  unsigned int* mrow = mx + (size_t)seg * 8;
#pragma unroll
  for (int h = 0; h < 8; ++h) atomicMax(&mrow[h], ordf(el[h]));
}

__global__ __launch_bounds__(256) void k_sum(const int* __restrict__ edge,
                                             const float* __restrict__ s_src,
                                             const float* __restrict__ s_dst,
                                             const unsigned int* __restrict__ mx,
                                             float* __restrict__ denom) {
  const int idx = blockIdx.x * 256 + threadIdx.x;
  float el[8];
  const int seg = edge_el(edge, s_src, s_dst, idx, el);
  const unsigned int* mrow = mx + (size_t)seg * 8;
  float* drow = denom + (size_t)seg * 8;
#pragma unroll
  for (int h = 0; h < 8; ++h) atomicAdd(&drow[h], __expf(el[h] - unordf(mrow[h])));
}

__global__ __launch_bounds__(256) void k_fin(const int* __restrict__ edge,
                                             const float* __restrict__ s_src,
                                             const float* __restrict__ s_dst,
                                             const unsigned int* __restrict__ mx,
                                             const float* __restrict__ denom,
                                             float* __restrict__ att) {
  const int idx = blockIdx.x * 256 + threadIdx.x;
  float el[8];
  const int seg = edge_el(edge, s_src, s_dst, idx, el);
  const unsigned int* mrow = mx + (size_t)seg * 8;
  const f4* drow = (const f4*)(denom + (size_t)seg * 8);
  f4 d0 = drow[0], d1 = drow[1];
  f4 o0, o1;
#pragma unroll
  for (int j = 0; j < 4; ++j) {
    o0[j] = __expf(el[j]     - unordf(mrow[j]))     / (d0[j] + 1e-16f);
    o1[j] = __expf(el[4 + j] - unordf(mrow[4 + j])) / (d1[j] + 1e-16f);
  }
  f4* op = (f4*)(att + (size_t)idx * 8);
  op[0] = o0;
  op[1] = o1;
}

extern "C" void kernel_launch(void* const* d_in, const int* in_sizes, int n_in,
                              void* d_out, int out_size, void* d_ws, size_t ws_size,
                              hipStream_t stream) {
  const float* x = (const float*)d_in[0];
  const int* edge = (const int*)d_in[1];
  const float* W = (const float*)d_in[2];
  const float* a = (const float*)d_in[3];

  float* att = (float*)d_out;                       // (B,E,H) = 10,240,000 f32
  float* wx = att + (size_t)BB * EE * HH;           // (B,N,256) = 10,240,000 f32

  char* ws = (char*)d_ws;
  unsigned short* Wt = (unsigned short*)ws;                 // 256*256*2 = 131072 B
  float* s_src = (float*)(ws + 131072);                     // 320000 f32
  float* s_dst = s_src + 320000;                            // 320000 f32
  unsigned int* mx = (unsigned int*)(s_dst + 320000);       // 320000 u32
  float* denom = (float*)(mx + 320000);                     // 320000 f32

  hipMemsetAsync(mx, 0, 320000 * sizeof(unsigned int), stream);   // ordf(-inf) < 0? no: 0 encodes below all reals
  hipMemsetAsync(denom, 0, 320000 * sizeof(float), stream);

  k_transpose<<<dim3(4, 4), 256, 0, stream>>>(W, Wt);
  k_gemm<<<625, 256, 0, stream>>>(x, Wt, wx);
  k_score<<<10000, 256, 0, stream>>>(wx, a, s_src, s_dst);
  k_max<<<5000, 256, 0, stream>>>(edge, s_src, s_dst, mx);
  k_sum<<<5000, 256, 0, stream>>>(edge, s_src, s_dst, mx, denom);
  k_fin<<<5000, 256, 0, stream>>>(edge, s_src, s_dst, mx, denom, att);
}

// Round 2
// 158.753 us; speedup vs baseline: 6.4836x; 6.4836x over previous
//
#include <hip/hip_runtime.h>
#include <hip/hip_bf16.h>

#define BB 4
#define NN 10000
#define EE 320000
#define HH 8
#define MAXE 96   // Poisson(32) tail over 40000 segments tops out ~65; 96 is safe

typedef float f4 __attribute__((ext_vector_type(4)));
typedef short s8v __attribute__((ext_vector_type(8)));
typedef unsigned short u16x8 __attribute__((ext_vector_type(8)));

__device__ __forceinline__ unsigned short f2bf(float f) {
  unsigned int u = __float_as_uint(f);
  u += 0x7FFFu + ((u >> 16) & 1u);
  return (unsigned short)(u >> 16);
}

// ---------------- W transpose + bf16 convert: Wt[n][k] = bf16(W[k][n]) ----------------
__global__ __launch_bounds__(256) void k_transpose(const float* __restrict__ W,
                                                   unsigned short* __restrict__ Wt) {
  __shared__ float tile[64][65];
  const int n0 = blockIdx.x * 64, k0 = blockIdx.y * 64;
  for (int i = threadIdx.x; i < 4096; i += 256) {
    int kk = i >> 6, nn = i & 63;
    tile[kk][nn] = W[(size_t)(k0 + kk) * 256 + n0 + nn];
  }
  __syncthreads();
  for (int i = threadIdx.x; i < 4096; i += 256) {
    int nn = i >> 6, kk = i & 63;
    Wt[(size_t)(n0 + nn) * 256 + (k0 + kk)] = f2bf(tile[kk][nn]);
  }
}

// ---------------- GEMM: wx[row][col] = sum_k x[row][k] * W[k][col], bf16 MFMA ----------------
__global__ __launch_bounds__(256, 2) void k_gemm(const float* __restrict__ x,
                                                 const unsigned short* __restrict__ Wt,
                                                 float* __restrict__ wx) {
  __shared__ unsigned short sA[64][40];   // [row][k], padded
  __shared__ unsigned short sB[256][40];  // [col][k] (= W^T), padded
  const int tid = threadIdx.x;
  const int lane = tid & 63;
  const int wv = tid >> 6;
  const int row0 = blockIdx.x << 6;
  const int fr = lane & 15;
  const int fg = lane >> 4;
  f4 acc[4][4] = {};
  const int ar = tid >> 2;
  const int ak = (tid & 3) << 3;

  for (int k0 = 0; k0 < 256; k0 += 32) {
    const float* xp = x + (size_t)(row0 + ar) * 256 + k0 + ak;
    f4 v0 = *(const f4*)xp;
    f4 v1 = *(const f4*)(xp + 4);
    u16x8 av;
    av[0] = f2bf(v0[0]); av[1] = f2bf(v0[1]); av[2] = f2bf(v0[2]); av[3] = f2bf(v0[3]);
    av[4] = f2bf(v1[0]); av[5] = f2bf(v1[1]); av[6] = f2bf(v1[2]); av[7] = f2bf(v1[3]);
    *(u16x8*)&sA[ar][ak] = av;
#pragma unroll
    for (int j = 0; j < 4; ++j) {
      int ci = tid + (j << 8);
      int col = ci >> 2;
      int ks = (ci & 3) << 3;
      *(u16x8*)&sB[col][ks] = *(const u16x8*)(Wt + (size_t)col * 256 + k0 + ks);
    }
    __syncthreads();
    s8v afr[4], bfr[4];
#pragma unroll
    for (int m = 0; m < 4; ++m) afr[m] = *(const s8v*)&sA[m * 16 + fr][fg << 3];
#pragma unroll
    for (int n = 0; n < 4; ++n) bfr[n] = *(const s8v*)&sB[wv * 64 + n * 16 + fr][fg << 3];
#pragma unroll
    for (int m = 0; m < 4; ++m)
#pragma unroll
      for (int n = 0; n < 4; ++n)
        acc[m][n] = __builtin_amdgcn_mfma_f32_16x16x32_bf16(afr[m], bfr[n], acc[m][n], 0, 0, 0);
    __syncthreads();
  }
#pragma unroll
  for (int m = 0; m < 4; ++m)
#pragma unroll
    for (int n = 0; n < 4; ++n) {
      int col = wv * 64 + n * 16 + fr;
#pragma unroll
      for (int q = 0; q < 4; ++q) {
        int row = row0 + m * 16 + fg * 4 + q;
        wx[(size_t)row * 256 + col] = acc[m][n][q];
      }
    }
}

// ---------------- per-node head scores ----------------
__global__ __launch_bounds__(256) void k_score(const float* __restrict__ wx,
                                               const float* __restrict__ a,
                                               float* __restrict__ s_src,
                                               float* __restrict__ s_dst) {
  const int row = blockIdx.x * 4 + (threadIdx.x >> 6);
  const int lane = threadIdx.x & 63;
  f4 v = *(const f4*)(wx + (size_t)row * 256 + lane * 4);
  const int head = lane >> 3;
  const int dk = (lane & 7) << 2;
  float ps = 0.f, pd = 0.f;
#pragma unroll
  for (int j = 0; j < 4; ++j) {
    ps += v[j] * a[dk + j];
    pd += v[j] * a[32 + dk + j];
  }
  ps += __shfl_xor(ps, 1); ps += __shfl_xor(ps, 2); ps += __shfl_xor(ps, 4);
  pd += __shfl_xor(pd, 1); pd += __shfl_xor(pd, 2); pd += __shfl_xor(pd, 4);
  if ((lane & 7) == 0) {
    s_src[(size_t)row * 8 + head] = ps;
    s_dst[(size_t)row * 8 + head] = pd;
  }
}

// ---------------- bucket edges by source segment (1 atomic per edge) ----------------
__global__ __launch_bounds__(256) void k_bucket(const int* __restrict__ edge,
                                                int* __restrict__ cnt,
                                                uint2* __restrict__ buckets) {
  const int idx = blockIdx.x * 256 + threadIdx.x;
  const int b = idx / EE;
  const int e = idx - b * EE;
  const int src = edge[(size_t)b * 2 * EE + e];
  const int dst = edge[(size_t)b * 2 * EE + EE + e];
  const int seg = b * NN + src;
  int p = atomicAdd(&cnt[seg], 1);
  if (p < MAXE) buckets[(size_t)seg * MAXE + p] = make_uint2((unsigned)idx, (unsigned)(b * NN + dst));
}

// ---------------- per-segment denom, atomic-free: one wave per segment ----------------
__global__ __launch_bounds__(256) void k_denom(const uint2* __restrict__ buckets,
                                               const int* __restrict__ cnt,
                                               const float* __restrict__ s_src,
                                               const float* __restrict__ s_dst,
                                               float* __restrict__ denom) {
  const int seg = blockIdx.x * 4 + (threadIdx.x >> 6);
  const int lane = threadIdx.x & 63;
  const int ei = lane >> 3;       // edge slot within 8-wide group
  const int h = lane & 7;         // head
  int n = cnt[seg]; if (n > MAXE) n = MAXE;
  const float ssrc = s_src[(size_t)seg * 8 + h];
  const uint2* bp = buckets + (size_t)seg * MAXE;
  float acc = 0.f;
  for (int base = 0; base < n; base += 8) {
    int i = base + ei;
    if (i < n) {
      uint2 p = bp[i];
      float v = ssrc + s_dst[(size_t)p.y * 8 + h];
      v = v >= 0.f ? v : 0.2f * v;
      acc += __expf(v);
    }
  }
  acc += __shfl_xor(acc, 8);
  acc += __shfl_xor(acc, 16);
  acc += __shfl_xor(acc, 32);
  if (lane < 8) denom[(size_t)seg * 8 + lane] = acc;
}

// ---------------- finalize: att = exp(el) / denom (no max shift; softmax is shift-invariant) ---
__global__ __launch_bounds__(256) void k_fin(const int* __restrict__ edge,
                                             const float* __restrict__ s_src,
                                             const float* __restrict__ s_dst,
                                             const float* __restrict__ denom,
                                             float* __restrict__ att) {
  const int idx = blockIdx.x * 256 + threadIdx.x;
  const int b = idx / EE;
  const int e = idx - b * EE;
  const int src = edge[(size_t)b * 2 * EE + e];
  const int dst = edge[(size_t)b * 2 * EE + EE + e];
  const int seg = b * NN + src;
  const f4* ss = (const f4*)(s_src + (size_t)seg * 8);
  const f4* sd = (const f4*)(s_dst + ((size_t)b * NN + dst) * 8);
  const f4* drow = (const f4*)(denom + (size_t)seg * 8);
  f4 a0 = ss[0] + sd[0];
  f4 a1 = ss[1] + sd[1];
  f4 d0 = drow[0], d1 = drow[1];
  f4 o0, o1;
#pragma unroll
  for (int j = 0; j < 4; ++j) {
    float t0 = a0[j]; t0 = t0 >= 0.f ? t0 : 0.2f * t0;
    float t1 = a1[j]; t1 = t1 >= 0.f ? t1 : 0.2f * t1;
    o0[j] = __expf(t0) / (d0[j] + 1e-16f);
    o1[j] = __expf(t1) / (d1[j] + 1e-16f);
  }
  f4* op = (f4*)(att + (size_t)idx * 8);
  op[0] = o0;
  op[1] = o1;
}

extern "C" void kernel_launch(void* const* d_in, const int* in_sizes, int n_in,
                              void* d_out, int out_size, void* d_ws, size_t ws_size,
                              hipStream_t stream) {
  const float* x = (const float*)d_in[0];
  const int* edge = (const int*)d_in[1];
  const float* W = (const float*)d_in[2];
  const float* a = (const float*)d_in[3];

  float* att = (float*)d_out;                       // (B,E,H) = 10,240,000 f32 = 41 MB
  float* wx = att + (size_t)BB * EE * HH;           // (B,N,256) = 10,240,000 f32

  // buckets live in the att output region (dead until k_fin overwrites it):
  // 40000 segs * 96 slots * 8 B = 30.72 MB < 41 MB
  uint2* buckets = (uint2*)att;

  char* ws = (char*)d_ws;
  unsigned short* Wt = (unsigned short*)ws;                 // 128 KiB
  float* s_src = (float*)(ws + 131072);                     // 320000 f32
  float* s_dst = s_src + 320000;                            // 320000 f32
  float* denom = s_dst + 320000;                            // 320000 f32
  int* cnt = (int*)(denom + 320000);                        // 40000 int

  hipMemsetAsync(cnt, 0, 40000 * sizeof(int), stream);

  k_transpose<<<dim3(4, 4), 256, 0, stream>>>(W, Wt);
  k_gemm<<<625, 256, 0, stream>>>(x, Wt, wx);
  k_score<<<10000, 256, 0, stream>>>(wx, a, s_src, s_dst);
  k_bucket<<<5000, 256, 0, stream>>>(edge, cnt, buckets);
  k_denom<<<10000, 256, 0, stream>>>(buckets, cnt, s_src, s_dst, denom);
  k_fin<<<5000, 256, 0, stream>>>(edge, s_src, s_dst, denom, att);
}

// Round 3
// 156.395 us; speedup vs baseline: 6.5814x; 1.0151x over previous
//
#include <hip/hip_runtime.h>
#include <hip/hip_bf16.h>

#define BB 4
#define NN 10000
#define EE 320000
#define HH 8
#define MAXE 96   // Poisson(32) tail over 40000 segments tops out ~65; 96 is safe

typedef float f4 __attribute__((ext_vector_type(4)));
typedef short s8v __attribute__((ext_vector_type(8)));
typedef unsigned short u16x8 __attribute__((ext_vector_type(8)));

__device__ __forceinline__ unsigned short f2bf(float f) {
  unsigned int u = __float_as_uint(f);
  u += 0x7FFFu + ((u >> 16) & 1u);
  return (unsigned short)(u >> 16);
}

// ---------------- W transpose + bf16 convert: Wt[n][k] = bf16(W[k][n]) ----------------
__global__ __launch_bounds__(256) void k_transpose(const float* __restrict__ W,
                                                   unsigned short* __restrict__ Wt) {
  __shared__ float tile[64][65];
  const int n0 = blockIdx.x * 64, k0 = blockIdx.y * 64;
  for (int i = threadIdx.x; i < 4096; i += 256) {
    int kk = i >> 6, nn = i & 63;
    tile[kk][nn] = W[(size_t)(k0 + kk) * 256 + n0 + nn];
  }
  __syncthreads();
  for (int i = threadIdx.x; i < 4096; i += 256) {
    int nn = i >> 6, kk = i & 63;
    Wt[(size_t)(n0 + nn) * 256 + (k0 + kk)] = f2bf(tile[kk][nn]);
  }
}

// ---- GEMM + fused score epilogue: wx = x@W (bf16 MFMA), s_src/s_dst per row/head ----
__global__ __launch_bounds__(256, 2) void k_gemm(const float* __restrict__ x,
                                                 const unsigned short* __restrict__ Wt,
                                                 const float* __restrict__ a,
                                                 float* __restrict__ wx,
                                                 float* __restrict__ s_src,
                                                 float* __restrict__ s_dst) {
  __shared__ unsigned short sA[64][40];   // [row][k], padded
  __shared__ unsigned short sB[256][40];  // [col][k] (= W^T), padded
  const int tid = threadIdx.x;
  const int lane = tid & 63;
  const int wv = tid >> 6;
  const int row0 = blockIdx.x << 6;
  const int fr = lane & 15;
  const int fg = lane >> 4;
  f4 acc[4][4] = {};
  const int ar = tid >> 2;
  const int ak = (tid & 3) << 3;

  for (int k0 = 0; k0 < 256; k0 += 32) {
    const float* xp = x + (size_t)(row0 + ar) * 256 + k0 + ak;
    f4 v0 = *(const f4*)xp;
    f4 v1 = *(const f4*)(xp + 4);
    u16x8 av;
    av[0] = f2bf(v0[0]); av[1] = f2bf(v0[1]); av[2] = f2bf(v0[2]); av[3] = f2bf(v0[3]);
    av[4] = f2bf(v1[0]); av[5] = f2bf(v1[1]); av[6] = f2bf(v1[2]); av[7] = f2bf(v1[3]);
    *(u16x8*)&sA[ar][ak] = av;
#pragma unroll
    for (int j = 0; j < 4; ++j) {
      int ci = tid + (j << 8);
      int col = ci >> 2;
      int ks = (ci & 3) << 3;
      *(u16x8*)&sB[col][ks] = *(const u16x8*)(Wt + (size_t)col * 256 + k0 + ks);
    }
    __syncthreads();
    s8v afr[4], bfr[4];
#pragma unroll
    for (int m = 0; m < 4; ++m) afr[m] = *(const s8v*)&sA[m * 16 + fr][fg << 3];
#pragma unroll
    for (int n = 0; n < 4; ++n) bfr[n] = *(const s8v*)&sB[wv * 64 + n * 16 + fr][fg << 3];
#pragma unroll
    for (int m = 0; m < 4; ++m)
#pragma unroll
      for (int n = 0; n < 4; ++n)
        acc[m][n] = __builtin_amdgcn_mfma_f32_16x16x32_bf16(afr[m], bfr[n], acc[m][n], 0, 0, 0);
    __syncthreads();
  }
  // C store: D[row][col], col = lane&15, row = (lane>>4)*4 + q
#pragma unroll
  for (int m = 0; m < 4; ++m)
#pragma unroll
    for (int n = 0; n < 4; ++n) {
      int col = wv * 64 + n * 16 + fr;
#pragma unroll
      for (int q = 0; q < 4; ++q) {
        int row = row0 + m * 16 + fg * 4 + q;
        wx[(size_t)row * 256 + col] = acc[m][n][q];
      }
    }
  // fused scores: wave wv owns heads {2wv, 2wv+1}; col = wv*64 + n*16 + fr -> dk = (n&1)*16+fr
  const float as0 = a[fr], as1 = a[16 + fr];
  const float ad0 = a[32 + fr], ad1 = a[48 + fr];
#pragma unroll
  for (int m = 0; m < 4; ++m)
#pragma unroll
    for (int q = 0; q < 4; ++q) {
      float p0 = acc[m][0][q] * as0 + acc[m][1][q] * as1;  // head 2wv, src
      float p1 = acc[m][2][q] * as0 + acc[m][3][q] * as1;  // head 2wv+1, src
      float d0 = acc[m][0][q] * ad0 + acc[m][1][q] * ad1;  // head 2wv, dst
      float d1 = acc[m][2][q] * ad0 + acc[m][3][q] * ad1;  // head 2wv+1, dst
#pragma unroll
      for (int msk = 1; msk <= 8; msk <<= 1) {
        p0 += __shfl_xor(p0, msk);
        p1 += __shfl_xor(p1, msk);
        d0 += __shfl_xor(d0, msk);
        d1 += __shfl_xor(d1, msk);
      }
      if (fr == 0) {
        int row = row0 + m * 16 + fg * 4 + q;
        s_src[(size_t)row * 8 + wv * 2]     = p0;
        s_src[(size_t)row * 8 + wv * 2 + 1] = p1;
        s_dst[(size_t)row * 8 + wv * 2]     = d0;
        s_dst[(size_t)row * 8 + wv * 2 + 1] = d1;
      }
    }
}

// ---------------- bucket edges by source segment: store dst only (ushort) ----------------
__global__ __launch_bounds__(256) void k_bucket(const int* __restrict__ edge,
                                                int* __restrict__ cnt,
                                                unsigned short* __restrict__ buckets) {
  const int idx = blockIdx.x * 256 + threadIdx.x;
  const int b = idx / EE;
  const int e = idx - b * EE;
  const int src = edge[(size_t)b * 2 * EE + e];
  const int dst = edge[(size_t)b * 2 * EE + EE + e];
  const int seg = b * NN + src;
  int p = atomicAdd(&cnt[seg], 1);
  if (p < MAXE) buckets[(size_t)seg * MAXE + p] = (unsigned short)dst;
}

// ---------------- per-segment denom, atomic-free: one wave per segment ----------------
__global__ __launch_bounds__(256) void k_denom(const unsigned short* __restrict__ buckets,
                                               const int* __restrict__ cnt,
                                               const float* __restrict__ s_src,
                                               const float* __restrict__ s_dst,
                                               float* __restrict__ denom) {
  const int seg = blockIdx.x * 4 + (threadIdx.x >> 6);
  const int lane = threadIdx.x & 63;
  const int ei = lane >> 3;       // edge slot within 8-wide group
  const int h = lane & 7;         // head
  int n = cnt[seg]; if (n > MAXE) n = MAXE;
  const int brow = (seg / NN) * NN;   // batch base row
  const float ssrc = s_src[(size_t)seg * 8 + h];
  const unsigned short* bp = buckets + (size_t)seg * MAXE;
  float acc = 0.f;
  for (int base = 0; base < n; base += 8) {
    int i = base + ei;
    if (i < n) {
      int dst = bp[i];
      float v = ssrc + s_dst[(size_t)(brow + dst) * 8 + h];
      v = v >= 0.f ? v : 0.2f * v;
      acc += __expf(v);
    }
  }
  acc += __shfl_xor(acc, 8);
  acc += __shfl_xor(acc, 16);
  acc += __shfl_xor(acc, 32);
  if (lane < 8) denom[(size_t)seg * 8 + lane] = acc;
}

// ---------------- finalize: att = exp(el) / denom (softmax is shift-invariant) ----------------
__global__ __launch_bounds__(256) void k_fin(const int* __restrict__ edge,
                                             const float* __restrict__ s_src,
                                             const float* __restrict__ s_dst,
                                             const float* __restrict__ denom,
                                             float* __restrict__ att) {
  const int idx = blockIdx.x * 256 + threadIdx.x;
  const int b = idx / EE;
  const int e = idx - b * EE;
  const int src = edge[(size_t)b * 2 * EE + e];
  const int dst = edge[(size_t)b * 2 * EE + EE + e];
  const int seg = b * NN + src;
  const f4* ss = (const f4*)(s_src + (size_t)seg * 8);
  const f4* sd = (const f4*)(s_dst + ((size_t)b * NN + dst) * 8);
  const f4* drow = (const f4*)(denom + (size_t)seg * 8);
  f4 a0 = ss[0] + sd[0];
  f4 a1 = ss[1] + sd[1];
  f4 d0 = drow[0], d1 = drow[1];
  f4 o0, o1;
#pragma unroll
  for (int j = 0; j < 4; ++j) {
    float t0 = a0[j]; t0 = t0 >= 0.f ? t0 : 0.2f * t0;
    float t1 = a1[j]; t1 = t1 >= 0.f ? t1 : 0.2f * t1;
    o0[j] = __expf(t0) / (d0[j] + 1e-16f);
    o1[j] = __expf(t1) / (d1[j] + 1e-16f);
  }
  f4* op = (f4*)(att + (size_t)idx * 8);
  op[0] = o0;
  op[1] = o1;
}

extern "C" void kernel_launch(void* const* d_in, const int* in_sizes, int n_in,
                              void* d_out, int out_size, void* d_ws, size_t ws_size,
                              hipStream_t stream) {
  const float* x = (const float*)d_in[0];
  const int* edge = (const int*)d_in[1];
  const float* W = (const float*)d_in[2];
  const float* a = (const float*)d_in[3];

  float* att = (float*)d_out;                       // (B,E,H) = 10,240,000 f32 = 41 MB
  float* wx = att + (size_t)BB * EE * HH;           // (B,N,256) = 10,240,000 f32

  // buckets live in the att output region (dead until k_fin overwrites it):
  // 40000 segs * 96 slots * 2 B = 7.68 MB < 41 MB
  unsigned short* buckets = (unsigned short*)att;

  char* ws = (char*)d_ws;
  unsigned short* Wt = (unsigned short*)ws;                 // 128 KiB
  float* s_src = (float*)(ws + 131072);                     // 320000 f32
  float* s_dst = s_src + 320000;                            // 320000 f32
  float* denom = s_dst + 320000;                            // 320000 f32
  int* cnt = (int*)(denom + 320000);                        // 40000 int

  hipMemsetAsync(cnt, 0, 40000 * sizeof(int), stream);

  k_transpose<<<dim3(4, 4), 256, 0, stream>>>(W, Wt);
  k_gemm<<<625, 256, 0, stream>>>(x, Wt, a, wx, s_src, s_dst);
  k_bucket<<<5000, 256, 0, stream>>>(edge, cnt, buckets);
  k_denom<<<10000, 256, 0, stream>>>(buckets, cnt, s_src, s_dst, denom);
  k_fin<<<5000, 256, 0, stream>>>(edge, s_src, s_dst, denom, att);
}

// Round 4
// 129.248 us; speedup vs baseline: 7.9637x; 1.2100x over previous
//
#include <hip/hip_runtime.h>
#include <hip/hip_bf16.h>

#define BB 4
#define NN 10000
#define EE 320000
#define HH 8
#define SEGH 5000      // segments per src-range (NN/2)
#define NSLICE 32      // edge slices per (batch, range)
#define ESL 10000      // edges per slice (EE/NSLICE)

typedef float f4 __attribute__((ext_vector_type(4)));
typedef short s8v __attribute__((ext_vector_type(8)));
typedef unsigned short u16x8 __attribute__((ext_vector_type(8)));

__device__ __forceinline__ unsigned short f2bf(float f) {
  unsigned int u = __float_as_uint(f);
  u += 0x7FFFu + ((u >> 16) & 1u);
  return (unsigned short)(u >> 16);
}

// ---------------- W transpose + bf16 convert: Wt[n][k] = bf16(W[k][n]) ----------------
__global__ __launch_bounds__(256) void k_transpose(const float* __restrict__ W,
                                                   unsigned short* __restrict__ Wt) {
  __shared__ float tile[64][65];
  const int n0 = blockIdx.x * 64, k0 = blockIdx.y * 64;
  for (int i = threadIdx.x; i < 4096; i += 256) {
    int kk = i >> 6, nn = i & 63;
    tile[kk][nn] = W[(size_t)(k0 + kk) * 256 + n0 + nn];
  }
  __syncthreads();
  for (int i = threadIdx.x; i < 4096; i += 256) {
    int nn = i >> 6, kk = i & 63;
    Wt[(size_t)(n0 + nn) * 256 + (k0 + kk)] = f2bf(tile[kk][nn]);
  }
}

// ---- GEMM + fused score epilogue: wx = x@W (bf16 MFMA), s_src/s_dst per row/head ----
__global__ __launch_bounds__(256, 2) void k_gemm(const float* __restrict__ x,
                                                 const unsigned short* __restrict__ Wt,
                                                 const float* __restrict__ a,
                                                 float* __restrict__ wx,
                                                 float* __restrict__ s_src,
                                                 float* __restrict__ s_dst) {
  __shared__ unsigned short sA[64][40];   // [row][k], padded
  __shared__ unsigned short sB[256][40];  // [col][k] (= W^T), padded
  const int tid = threadIdx.x;
  const int lane = tid & 63;
  const int wv = tid >> 6;
  const int row0 = blockIdx.x << 6;
  const int fr = lane & 15;
  const int fg = lane >> 4;
  f4 acc[4][4] = {};
  const int ar = tid >> 2;
  const int ak = (tid & 3) << 3;

  for (int k0 = 0; k0 < 256; k0 += 32) {
    const float* xp = x + (size_t)(row0 + ar) * 256 + k0 + ak;
    f4 v0 = *(const f4*)xp;
    f4 v1 = *(const f4*)(xp + 4);
    u16x8 av;
    av[0] = f2bf(v0[0]); av[1] = f2bf(v0[1]); av[2] = f2bf(v0[2]); av[3] = f2bf(v0[3]);
    av[4] = f2bf(v1[0]); av[5] = f2bf(v1[1]); av[6] = f2bf(v1[2]); av[7] = f2bf(v1[3]);
    *(u16x8*)&sA[ar][ak] = av;
#pragma unroll
    for (int j = 0; j < 4; ++j) {
      int ci = tid + (j << 8);
      int col = ci >> 2;
      int ks = (ci & 3) << 3;
      *(u16x8*)&sB[col][ks] = *(const u16x8*)(Wt + (size_t)col * 256 + k0 + ks);
    }
    __syncthreads();
    s8v afr[4], bfr[4];
#pragma unroll
    for (int m = 0; m < 4; ++m) afr[m] = *(const s8v*)&sA[m * 16 + fr][fg << 3];
#pragma unroll
    for (int n = 0; n < 4; ++n) bfr[n] = *(const s8v*)&sB[wv * 64 + n * 16 + fr][fg << 3];
#pragma unroll
    for (int m = 0; m < 4; ++m)
#pragma unroll
      for (int n = 0; n < 4; ++n)
        acc[m][n] = __builtin_amdgcn_mfma_f32_16x16x32_bf16(afr[m], bfr[n], acc[m][n], 0, 0, 0);
    __syncthreads();
  }
  // C store: D[row][col], col = lane&15, row = (lane>>4)*4 + q
#pragma unroll
  for (int m = 0; m < 4; ++m)
#pragma unroll
    for (int n = 0; n < 4; ++n) {
      int col = wv * 64 + n * 16 + fr;
#pragma unroll
      for (int q = 0; q < 4; ++q) {
        int row = row0 + m * 16 + fg * 4 + q;
        wx[(size_t)row * 256 + col] = acc[m][n][q];
      }
    }
  // fused scores: wave wv owns heads {2wv, 2wv+1}
  const float as0 = a[fr], as1 = a[16 + fr];
  const float ad0 = a[32 + fr], ad1 = a[48 + fr];
#pragma unroll
  for (int m = 0; m < 4; ++m)
#pragma unroll
    for (int q = 0; q < 4; ++q) {
      float p0 = acc[m][0][q] * as0 + acc[m][1][q] * as1;
      float p1 = acc[m][2][q] * as0 + acc[m][3][q] * as1;
      float d0 = acc[m][0][q] * ad0 + acc[m][1][q] * ad1;
      float d1 = acc[m][2][q] * ad0 + acc[m][3][q] * ad1;
#pragma unroll
      for (int msk = 1; msk <= 8; msk <<= 1) {
        p0 += __shfl_xor(p0, msk);
        p1 += __shfl_xor(p1, msk);
        d0 += __shfl_xor(d0, msk);
        d1 += __shfl_xor(d1, msk);
      }
      if (fr == 0) {
        int row = row0 + m * 16 + fg * 4 + q;
        s_src[(size_t)row * 8 + wv * 2]     = p0;
        s_src[(size_t)row * 8 + wv * 2 + 1] = p1;
        s_dst[(size_t)row * 8 + wv * 2]     = d0;
        s_dst[(size_t)row * 8 + wv * 2 + 1] = d1;
      }
    }
}

// ---- LDS-privatized denom binning: block = (batch, src-range, edge-slice) ----
// LDS = SEGH*8 f32 = 160000 B. Partials written densely; no global atomics.
__global__ __launch_bounds__(1024) void k_bin(const int* __restrict__ edge,
                                              const float* __restrict__ s_src,
                                              const float* __restrict__ s_dst,
                                              float* __restrict__ partial) {
  extern __shared__ float lds[];
  const int blk = blockIdx.x;          // ((b*2+hf)*NSLICE + r)
  const int r = blk & (NSLICE - 1);
  const int bh = blk / NSLICE;
  const int hf = bh & 1;
  const int b = bh >> 1;
  const int tid = threadIdx.x;
  for (int i = tid; i < SEGH * 8; i += 1024) lds[i] = 0.f;
  __syncthreads();
  const int ebase = r * ESL;
  const int lo = hf * SEGH;
  for (int i = tid; i < ESL; i += 1024) {
    const int e = ebase + i;
    const int src = edge[(size_t)b * 2 * EE + e];
    const int dst = edge[(size_t)b * 2 * EE + EE + e];
    const int ls = src - lo;
    if ((unsigned)ls < (unsigned)SEGH) {
      const f4* ss = (const f4*)(s_src + ((size_t)b * NN + src) * 8);
      const f4* sd = (const f4*)(s_dst + ((size_t)b * NN + dst) * 8);
      f4 a0 = ss[0] + sd[0];
      f4 a1 = ss[1] + sd[1];
#pragma unroll
      for (int j = 0; j < 4; ++j) {
        float t0 = a0[j]; t0 = t0 >= 0.f ? t0 : 0.2f * t0;
        float t1 = a1[j]; t1 = t1 >= 0.f ? t1 : 0.2f * t1;
        atomicAdd(&lds[ls * 8 + j],     __expf(t0));
        atomicAdd(&lds[ls * 8 + 4 + j], __expf(t1));
      }
    }
  }
  __syncthreads();
  f4* pout = (f4*)(partial + (size_t)blk * (SEGH * 8));
  const f4* lin = (const f4*)lds;
  for (int i = tid; i < SEGH * 2; i += 1024) pout[i] = lin[i];
}

// ---- reduce 32 slice-partials -> denom, fully coalesced, no atomics ----
__global__ __launch_bounds__(256) void k_reduce(const float* __restrict__ partial,
                                                float* __restrict__ denom) {
  const int t = blockIdx.x * 256 + threadIdx.x;    // f4 units: 8 combos * SEGH*2
  if (t >= 8 * SEGH * 2) return;
  const int c = t / (SEGH * 2);        // combo = b*2+hf
  const int i4 = t - c * (SEGH * 2);   // 0..SEGH*2-1
  const f4* pp = (const f4*)partial;
  f4 s = {0.f, 0.f, 0.f, 0.f};
#pragma unroll 8
  for (int r = 0; r < NSLICE; ++r)
    s += pp[((size_t)(c * NSLICE + r)) * (SEGH * 2) + i4];
  const int b = c >> 1, hf = c & 1;
  const int ls = i4 >> 1, hh = i4 & 1;
  ((f4*)denom)[((size_t)b * NN + hf * SEGH + ls) * 2 + hh] = s;
}

// ---------------- finalize: att = exp(el) / denom (softmax is shift-invariant) ----------------
__global__ __launch_bounds__(256) void k_fin(const int* __restrict__ edge,
                                             const float* __restrict__ s_src,
                                             const float* __restrict__ s_dst,
                                             const float* __restrict__ denom,
                                             float* __restrict__ att) {
  const int idx = blockIdx.x * 256 + threadIdx.x;
  const int b = idx / EE;
  const int e = idx - b * EE;
  const int src = edge[(size_t)b * 2 * EE + e];
  const int dst = edge[(size_t)b * 2 * EE + EE + e];
  const int seg = b * NN + src;
  const f4* ss = (const f4*)(s_src + (size_t)seg * 8);
  const f4* sd = (const f4*)(s_dst + ((size_t)b * NN + dst) * 8);
  const f4* drow = (const f4*)(denom + (size_t)seg * 8);
  f4 a0 = ss[0] + sd[0];
  f4 a1 = ss[1] + sd[1];
  f4 d0 = drow[0], d1 = drow[1];
  f4 o0, o1;
#pragma unroll
  for (int j = 0; j < 4; ++j) {
    float t0 = a0[j]; t0 = t0 >= 0.f ? t0 : 0.2f * t0;
    float t1 = a1[j]; t1 = t1 >= 0.f ? t1 : 0.2f * t1;
    o0[j] = __expf(t0) / (d0[j] + 1e-16f);
    o1[j] = __expf(t1) / (d1[j] + 1e-16f);
  }
  f4* op = (f4*)(att + (size_t)idx * 8);
  op[0] = o0;
  op[1] = o1;
}

extern "C" void kernel_launch(void* const* d_in, const int* in_sizes, int n_in,
                              void* d_out, int out_size, void* d_ws, size_t ws_size,
                              hipStream_t stream) {
  const float* x = (const float*)d_in[0];
  const int* edge = (const int*)d_in[1];
  const float* W = (const float*)d_in[2];
  const float* a = (const float*)d_in[3];

  float* att = (float*)d_out;                       // (B,E,H) = 10,240,000 f32 = 40.96 MB
  float* wx = att + (size_t)BB * EE * HH;           // (B,N,256) = 10,240,000 f32

  // partial histograms live in the att output region (dead until k_fin):
  // 256 blocks * 160000 B = 40,960,000 B == att size exactly.
  float* partial = att;

  char* ws = (char*)d_ws;
  unsigned short* Wt = (unsigned short*)ws;                 // 128 KiB
  float* s_src = (float*)(ws + 131072);                     // 320000 f32
  float* s_dst = s_src + 320000;                            // 320000 f32
  float* denom = s_dst + 320000;                            // 320000 f32

  hipFuncSetAttribute((const void*)k_bin, hipFuncAttributeMaxDynamicSharedMemorySize, SEGH * 8 * 4);

  k_transpose<<<dim3(4, 4), 256, 0, stream>>>(W, Wt);
  k_gemm<<<625, 256, 0, stream>>>(x, Wt, a, wx, s_src, s_dst);
  k_bin<<<BB * 2 * NSLICE, 1024, SEGH * 8 * 4, stream>>>(edge, s_src, s_dst, partial);
  k_reduce<<<(8 * SEGH * 2 + 255) / 256, 256, 0, stream>>>(partial, denom);
  k_fin<<<5000, 256, 0, stream>>>(edge, s_src, s_dst, denom, att);
}

// Round 5
// 123.138 us; speedup vs baseline: 8.3588x; 1.0496x over previous
//
#include <hip/hip_runtime.h>
#include <hip/hip_bf16.h>

#define BB 4
#define NN 10000
#define EE 320000
#define HH 8
#define NSLICE 16            // edge slices per (batch, head-pair)
#define ESL (EE / NSLICE)    // 20000 edges per slice

typedef float f4 __attribute__((ext_vector_type(4)));
typedef short s8v __attribute__((ext_vector_type(8)));
typedef unsigned short u16x8 __attribute__((ext_vector_type(8)));

__device__ __forceinline__ unsigned short f2bf(float f) {
  unsigned int u = __float_as_uint(f);
  u += 0x7FFFu + ((u >> 16) & 1u);
  return (unsigned short)(u >> 16);
}

// ---------------- W transpose + bf16 convert: Wt[n][k] = bf16(W[k][n]) ----------------
__global__ __launch_bounds__(256) void k_transpose(const float* __restrict__ W,
                                                   unsigned short* __restrict__ Wt) {
  __shared__ float tile[64][65];
  const int n0 = blockIdx.x * 64, k0 = blockIdx.y * 64;
  for (int i = threadIdx.x; i < 4096; i += 256) {
    int kk = i >> 6, nn = i & 63;
    tile[kk][nn] = W[(size_t)(k0 + kk) * 256 + n0 + nn];
  }
  __syncthreads();
  for (int i = threadIdx.x; i < 4096; i += 256) {
    int nn = i >> 6, kk = i & 63;
    Wt[(size_t)(n0 + nn) * 256 + (k0 + kk)] = f2bf(tile[kk][nn]);
  }
}

// ---- GEMM + fused score epilogue: wx = x@W (bf16 MFMA), s_src/s_dst per row/head ----
__global__ __launch_bounds__(256, 2) void k_gemm(const float* __restrict__ x,
                                                 const unsigned short* __restrict__ Wt,
                                                 const float* __restrict__ a,
                                                 float* __restrict__ wx,
                                                 float* __restrict__ s_src,
                                                 float* __restrict__ s_dst) {
  __shared__ unsigned short sA[64][40];   // [row][k], padded
  __shared__ unsigned short sB[256][40];  // [col][k] (= W^T), padded
  const int tid = threadIdx.x;
  const int lane = tid & 63;
  const int wv = tid >> 6;
  const int row0 = blockIdx.x << 6;
  const int fr = lane & 15;
  const int fg = lane >> 4;
  f4 acc[4][4] = {};
  const int ar = tid >> 2;
  const int ak = (tid & 3) << 3;

  for (int k0 = 0; k0 < 256; k0 += 32) {
    const float* xp = x + (size_t)(row0 + ar) * 256 + k0 + ak;
    f4 v0 = *(const f4*)xp;
    f4 v1 = *(const f4*)(xp + 4);
    u16x8 av;
    av[0] = f2bf(v0[0]); av[1] = f2bf(v0[1]); av[2] = f2bf(v0[2]); av[3] = f2bf(v0[3]);
    av[4] = f2bf(v1[0]); av[5] = f2bf(v1[1]); av[6] = f2bf(v1[2]); av[7] = f2bf(v1[3]);
    *(u16x8*)&sA[ar][ak] = av;
#pragma unroll
    for (int j = 0; j < 4; ++j) {
      int ci = tid + (j << 8);
      int col = ci >> 2;
      int ks = (ci & 3) << 3;
      *(u16x8*)&sB[col][ks] = *(const u16x8*)(Wt + (size_t)col * 256 + k0 + ks);
    }
    __syncthreads();
    s8v afr[4], bfr[4];
#pragma unroll
    for (int m = 0; m < 4; ++m) afr[m] = *(const s8v*)&sA[m * 16 + fr][fg << 3];
#pragma unroll
    for (int n = 0; n < 4; ++n) bfr[n] = *(const s8v*)&sB[wv * 64 + n * 16 + fr][fg << 3];
#pragma unroll
    for (int m = 0; m < 4; ++m)
#pragma unroll
      for (int n = 0; n < 4; ++n)
        acc[m][n] = __builtin_amdgcn_mfma_f32_16x16x32_bf16(afr[m], bfr[n], acc[m][n], 0, 0, 0);
    __syncthreads();
  }
  // C store: D[row][col], col = lane&15, row = (lane>>4)*4 + q
#pragma unroll
  for (int m = 0; m < 4; ++m)
#pragma unroll
    for (int n = 0; n < 4; ++n) {
      int col = wv * 64 + n * 16 + fr;
#pragma unroll
      for (int q = 0; q < 4; ++q) {
        int row = row0 + m * 16 + fg * 4 + q;
        wx[(size_t)row * 256 + col] = acc[m][n][q];
      }
    }
  // fused scores: wave wv owns heads {2wv, 2wv+1}
  const float as0 = a[fr], as1 = a[16 + fr];
  const float ad0 = a[32 + fr], ad1 = a[48 + fr];
#pragma unroll
  for (int m = 0; m < 4; ++m)
#pragma unroll
    for (int q = 0; q < 4; ++q) {
      float p0 = acc[m][0][q] * as0 + acc[m][1][q] * as1;
      float p1 = acc[m][2][q] * as0 + acc[m][3][q] * as1;
      float d0 = acc[m][0][q] * ad0 + acc[m][1][q] * ad1;
      float d1 = acc[m][2][q] * ad0 + acc[m][3][q] * ad1;
#pragma unroll
      for (int msk = 1; msk <= 8; msk <<= 1) {
        p0 += __shfl_xor(p0, msk);
        p1 += __shfl_xor(p1, msk);
        d0 += __shfl_xor(d0, msk);
        d1 += __shfl_xor(d1, msk);
      }
      if (fr == 0) {
        int row = row0 + m * 16 + fg * 4 + q;
        s_src[(size_t)row * 8 + wv * 2]     = p0;
        s_src[(size_t)row * 8 + wv * 2 + 1] = p1;
        s_dst[(size_t)row * 8 + wv * 2]     = d0;
        s_dst[(size_t)row * 8 + wv * 2 + 1] = d1;
      }
    }
}

// ---- LDS-privatized denom binning: block = (batch, head-pair, edge-slice) ----
// LDS = 2 heads * NN segments * f32 = 80 KB -> 2 blocks/CU, 32 waves/CU.
// SoA layout lds[h][seg]: ds_add bank = seg % 32 (uniform) instead of 4-bank AoS.
__global__ __launch_bounds__(1024) void k_bin(const int* __restrict__ edge,
                                              const float* __restrict__ s_src,
                                              const float* __restrict__ s_dst,
                                              float* __restrict__ partial) {
  extern __shared__ float lds[];       // [2][NN]
  const int blk = blockIdx.x;          // ((b*4+hp)*NSLICE + r)
  const int r = blk & (NSLICE - 1);
  const int bh = blk / NSLICE;
  const int hp = bh & 3;
  const int b = bh >> 2;
  const int tid = threadIdx.x;
  for (int i = tid; i < 2 * NN; i += 1024) lds[i] = 0.f;
  __syncthreads();
  const int ebase = r * ESL;
  const int* ep = edge + (size_t)b * 2 * EE;
  const float* ss_base = s_src + 2 * hp;
  const float* sd_base = s_dst + 2 * hp;
  for (int i = tid; i < ESL; i += 1024) {
    const int e = ebase + i;
    const int src = ep[e];
    const int dst = ep[EE + e];
    const float2 ss = *(const float2*)(ss_base + ((size_t)b * NN + src) * 8);
    const float2 sd = *(const float2*)(sd_base + ((size_t)b * NN + dst) * 8);
    float t0 = ss.x + sd.x; t0 = t0 >= 0.f ? t0 : 0.2f * t0;
    float t1 = ss.y + sd.y; t1 = t1 >= 0.f ? t1 : 0.2f * t1;
    atomicAdd(&lds[src], __expf(t0));
    atomicAdd(&lds[NN + src], __expf(t1));
  }
  __syncthreads();
  f4* pout = (f4*)(partial + (size_t)blk * (2 * NN));
  const f4* lin = (const f4*)lds;
  for (int i = tid; i < 2 * NN / 4; i += 1024) pout[i] = lin[i];
}

// ---- reduce NSLICE slice-partials -> denom, coalesced, no atomics ----
__global__ __launch_bounds__(256) void k_reduce(const float* __restrict__ partial,
                                                float* __restrict__ denom) {
  const int t = blockIdx.x * 256 + threadIdx.x;   // (b*4+hp)*NN + seg, 160000 total
  if (t >= 16 * NN) return;
  const int seg = t % NN;
  const int c = t / NN;                // c = b*4+hp
  const float* pp = partial + (size_t)c * NSLICE * 2 * NN;
  float s0 = 0.f, s1 = 0.f;
#pragma unroll 4
  for (int r = 0; r < NSLICE; ++r) {
    s0 += pp[(size_t)r * 2 * NN + seg];
    s1 += pp[(size_t)r * 2 * NN + NN + seg];
  }
  const int b = c >> 2, hp = c & 3;
  *(float2*)(denom + ((size_t)b * NN + seg) * 8 + 2 * hp) = make_float2(s0, s1);
}

// ---------------- finalize: att = exp(el) / denom (softmax is shift-invariant) ----------------
__global__ __launch_bounds__(256) void k_fin(const int* __restrict__ edge,
                                             const float* __restrict__ s_src,
                                             const float* __restrict__ s_dst,
                                             const float* __restrict__ denom,
                                             float* __restrict__ att) {
  const int idx = blockIdx.x * 256 + threadIdx.x;
  const int b = idx / EE;
  const int e = idx - b * EE;
  const int src = edge[(size_t)b * 2 * EE + e];
  const int dst = edge[(size_t)b * 2 * EE + EE + e];
  const int seg = b * NN + src;
  const f4* ss = (const f4*)(s_src + (size_t)seg * 8);
  const f4* sd = (const f4*)(s_dst + ((size_t)b * NN + dst) * 8);
  const f4* drow = (const f4*)(denom + (size_t)seg * 8);
  f4 a0 = ss[0] + sd[0];
  f4 a1 = ss[1] + sd[1];
  f4 d0 = drow[0], d1 = drow[1];
  f4 o0, o1;
#pragma unroll
  for (int j = 0; j < 4; ++j) {
    float t0 = a0[j]; t0 = t0 >= 0.f ? t0 : 0.2f * t0;
    float t1 = a1[j]; t1 = t1 >= 0.f ? t1 : 0.2f * t1;
    o0[j] = __expf(t0) / (d0[j] + 1e-16f);
    o1[j] = __expf(t1) / (d1[j] + 1e-16f);
  }
  f4* op = (f4*)(att + (size_t)idx * 8);
  op[0] = o0;
  op[1] = o1;
}

extern "C" void kernel_launch(void* const* d_in, const int* in_sizes, int n_in,
                              void* d_out, int out_size, void* d_ws, size_t ws_size,
                              hipStream_t stream) {
  const float* x = (const float*)d_in[0];
  const int* edge = (const int*)d_in[1];
  const float* W = (const float*)d_in[2];
  const float* a = (const float*)d_in[3];

  float* att = (float*)d_out;                       // (B,E,H) = 10,240,000 f32 = 40.96 MB
  float* wx = att + (size_t)BB * EE * HH;           // (B,N,256) = 10,240,000 f32

  // partial histograms live in the att output region (dead until k_fin):
  // 256 blocks * 80000 B = 20.48 MB < 40.96 MB.
  float* partial = att;

  char* ws = (char*)d_ws;
  unsigned short* Wt = (unsigned short*)ws;                 // 128 KiB
  float* s_src = (float*)(ws + 131072);                     // 320000 f32
  float* s_dst = s_src + 320000;                            // 320000 f32
  float* denom = s_dst + 320000;                            // 320000 f32

  hipFuncSetAttribute((const void*)k_bin, hipFuncAttributeMaxDynamicSharedMemorySize, 2 * NN * 4);

  k_transpose<<<dim3(4, 4), 256, 0, stream>>>(W, Wt);
  k_gemm<<<625, 256, 0, stream>>>(x, Wt, a, wx, s_src, s_dst);
  k_bin<<<BB * 4 * NSLICE, 1024, 2 * NN * 4, stream>>>(edge, s_src, s_dst, partial);
  k_reduce<<<(16 * NN + 255) / 256, 256, 0, stream>>>(partial, denom);
  k_fin<<<5000, 256, 0, stream>>>(edge, s_src, s_dst, denom, att);
}